// Round 9
// baseline (488.340 us; speedup 1.0000x reference)
//
#include <hip/hip_runtime.h>

typedef unsigned short ushort_t;
typedef __attribute__((ext_vector_type(8))) short short8;
typedef __attribute__((ext_vector_type(4))) float f32x4;
typedef __attribute__((ext_vector_type(2))) unsigned uint2v;

#define B_ 4
#define T_ 2048
#define D_ 1024
#define F_ 4096
#define M_ (B_*T_)
#define CH_ 64
#define NC_ (T_/CH_)   // 32 chunks

#define AS1 __attribute__((address_space(1)))
#define AS3 __attribute__((address_space(3)))

__device__ __forceinline__ ushort_t f2bf(float f) {
  union { float f; unsigned u; } a; a.f = f;
  unsigned r = a.u + 0x7FFFu + ((a.u >> 16) & 1u);
  return (ushort_t)(r >> 16);
}

__device__ __forceinline__ float bf2f(ushort_t u) {
  union { unsigned u; float f; } a; a.u = ((unsigned)u) << 16;
  return a.f;
}

__device__ __forceinline__ void nt_store_us4(ushort_t* p, ushort4 v) {
  __builtin_nontemporal_store(*(const uint2v*)&v, (uint2v*)p);
}

__device__ __forceinline__ void gl_lds16(const void* g, void* l) {
  __builtin_amdgcn_global_load_lds((AS1 void*)(__UINTPTR_TYPE__)g,
                                   (AS3 void*)l, 16, 0, 0);
}

// XCD-chunked bijective swizzle (T1) + 4x4 block supertiles inside each XCD
// chunk (keeps A-panels x B-panels working set ~4MB = L2-resident).
// Valid for gy == 4 or gy % 4 == 0, nwg % 8 == 0.
__device__ __forceinline__ void xcd_swz(int gx, int gy, int& bx, int& by, int& bz) {
  int lid = blockIdx.x + gx * (blockIdx.y + gy * blockIdx.z);
  int nwg = gx * gy * gridDim.z;
  int cpx = nwg >> 3;
  int L = (lid & 7) * cpx + (lid >> 3);
  int gy4 = (gy >= 4) ? (gy >> 2) : 1;
  by = (L & 3) + 4 * ((L >> 4) % gy4);
  int bxz = ((L >> 2) & 3) + 4 * (L / (4 * gy));
  bx = bxz % gx;
  bz = bxz / gx;
}

// ---------------- transpose + f32->bf16 convert: Wt[n][k] = W[k][n] ----------------
__global__ __launch_bounds__(256) void tconv(const float* __restrict__ W,
                                             ushort_t* __restrict__ Wt,
                                             int K, int N) {
  __shared__ float tile[32][33];
  int tx = threadIdx.x, ty = threadIdx.y;
  int n0 = blockIdx.x * 32, k0 = blockIdx.y * 32;
  #pragma unroll
  for (int i = 0; i < 32; i += 8)
    tile[ty + i][tx] = W[(size_t)(k0 + ty + i) * N + n0 + tx];
  __syncthreads();
  #pragma unroll
  for (int i = 0; i < 32; i += 8)
    Wt[(size_t)(n0 + ty + i) * K + k0 + tx] = f2bf(tile[tx][ty + i]);
}

// batched D x D transposes (z selects src/dst)
__global__ __launch_bounds__(256) void tconv5(const float* __restrict__ s0,
                                              const float* __restrict__ s1,
                                              const float* __restrict__ s2,
                                              const float* __restrict__ s3,
                                              const float* __restrict__ s4,
                                              ushort_t* __restrict__ d0,
                                              ushort_t* __restrict__ d1,
                                              ushort_t* __restrict__ d2,
                                              ushort_t* __restrict__ d3,
                                              ushort_t* __restrict__ d4) {
  __shared__ float tile[32][33];
  int z = blockIdx.z;
  const float* W = (z == 0) ? s0 : (z == 1) ? s1 : (z == 2) ? s2 : (z == 3) ? s3 : s4;
  ushort_t* Wt   = (z == 0) ? d0 : (z == 1) ? d1 : (z == 2) ? d2 : (z == 3) ? d3 : d4;
  int tx = threadIdx.x, ty = threadIdx.y;
  int n0 = blockIdx.x * 32, k0 = blockIdx.y * 32;
  #pragma unroll
  for (int i = 0; i < 32; i += 8)
    tile[ty + i][tx] = W[(size_t)(k0 + ty + i) * D_ + n0 + tx];
  __syncthreads();
  #pragma unroll
  for (int i = 0; i < 32; i += 8)
    Wt[(size_t)(n0 + ty + i) * D_ + k0 + tx] = f2bf(tile[tx][ty + i]);
}

// ---------------- fused LayerNorm + token-shift mix ----------------
#define MIX1(c, p, f) f2bf((c) * (f) + (p) * (1.0f - (f)))

template <int NOUT>
__global__ __launch_bounds__(256)
void ln_mix(const float* __restrict__ xin, const float* __restrict__ st,
            const float* __restrict__ g, const float* __restrict__ bb,
            const float* __restrict__ mk, const float* __restrict__ mv,
            const float* __restrict__ mr,
            ushort_t* __restrict__ ok, ushort_t* __restrict__ ov,
            ushort_t* __restrict__ orr, float* __restrict__ last) {
  int row = blockIdx.x;                  // b*T + t
  int t = row & (T_ - 1);
  int b = row >> 11;
  int tid = threadIdx.x;
  const bool pln = (t != 0);
  float4 vc = ((const float4*)(xin + (size_t)row * D_))[tid];
  float4 vp = pln ? ((const float4*)(xin + (size_t)(row - 1) * D_))[tid]
                  : ((const float4*)(st + (size_t)b * D_))[tid];
  float s0 = vc.x + vc.y + vc.z + vc.w;
  float s1 = vc.x * vc.x + vc.y * vc.y + vc.z * vc.z + vc.w * vc.w;
  float s2 = vp.x + vp.y + vp.z + vp.w;
  float s3 = vp.x * vp.x + vp.y * vp.y + vp.z * vp.z + vp.w * vp.w;
  #pragma unroll
  for (int o = 32; o > 0; o >>= 1) {
    s0 += __shfl_down(s0, o); s1 += __shfl_down(s1, o);
    s2 += __shfl_down(s2, o); s3 += __shfl_down(s3, o);
  }
  __shared__ float red[4][4];
  if ((tid & 63) == 0) {
    int w = tid >> 6;
    red[w][0] = s0; red[w][1] = s1; red[w][2] = s2; red[w][3] = s3;
  }
  __syncthreads();
  float cs0 = red[0][0] + red[1][0] + red[2][0] + red[3][0];
  float cs1 = red[0][1] + red[1][1] + red[2][1] + red[3][1];
  float ps0 = red[0][2] + red[1][2] + red[2][2] + red[3][2];
  float ps1 = red[0][3] + red[1][3] + red[2][3] + red[3][3];

  float mu = cs0 * (1.0f / D_);
  float rs = rsqrtf(cs1 * (1.0f / D_) - mu * mu + 1e-3f);
  float4 gv = ((const float4*)g)[tid];
  float4 bv = ((const float4*)bb)[tid];
  float hc[4], hp[4];
  hc[0] = (vc.x - mu) * rs * gv.x + bv.x;
  hc[1] = (vc.y - mu) * rs * gv.y + bv.y;
  hc[2] = (vc.z - mu) * rs * gv.z + bv.z;
  hc[3] = (vc.w - mu) * rs * gv.w + bv.w;
  if (pln) {
    float mup = ps0 * (1.0f / D_);
    float rsp = rsqrtf(ps1 * (1.0f / D_) - mup * mup + 1e-3f);
    hp[0] = (vp.x - mup) * rsp * gv.x + bv.x;
    hp[1] = (vp.y - mup) * rsp * gv.y + bv.y;
    hp[2] = (vp.z - mup) * rsp * gv.z + bv.z;
    hp[3] = (vp.w - mup) * rsp * gv.w + bv.w;
  } else {
    hp[0] = vp.x; hp[1] = vp.y; hp[2] = vp.z; hp[3] = vp.w;
  }

  size_t qi = (size_t)row * 256 + tid;   // ushort4 index
  float4 k4 = ((const float4*)mk)[tid];
  float4 r4 = ((const float4*)mr)[tid];
  ushort4 o4;
  o4.x = MIX1(hc[0], hp[0], k4.x); o4.y = MIX1(hc[1], hp[1], k4.y);
  o4.z = MIX1(hc[2], hp[2], k4.z); o4.w = MIX1(hc[3], hp[3], k4.w);
  nt_store_us4(ok + qi * 4, o4);
  if (NOUT == 3) {
    float4 v4 = ((const float4*)mv)[tid];
    o4.x = MIX1(hc[0], hp[0], v4.x); o4.y = MIX1(hc[1], hp[1], v4.y);
    o4.z = MIX1(hc[2], hp[2], v4.z); o4.w = MIX1(hc[3], hp[3], v4.w);
    nt_store_us4(ov + qi * 4, o4);
  }
  o4.x = MIX1(hc[0], hp[0], r4.x); o4.y = MIX1(hc[1], hp[1], r4.y);
  o4.z = MIX1(hc[2], hp[2], r4.z); o4.w = MIX1(hc[3], hp[3], r4.w);
  nt_store_us4(orr + qi * 4, o4);

  if (t == T_ - 1) {
    float4 h4; h4.x = hc[0]; h4.y = hc[1]; h4.z = hc[2]; h4.w = hc[3];
    ((float4*)(last + (size_t)b * D_))[tid] = h4;
  }
}

// ---------------- WKV chunked parallel scan (bf16 k/v; r from f32 partials) -------
__global__ __launch_bounds__(256) void wkv_part1(const ushort_t* __restrict__ k,
                                                 const ushort_t* __restrict__ v,
                                                 const float* __restrict__ tdec,
                                                 float* __restrict__ cn,
                                                 float* __restrict__ cd,
                                                 float* __restrict__ cq) {
  int idx = blockIdx.x * 256 + threadIdx.x;      // [c][b][d]
  int d = idx & (D_ - 1);
  int b = (idx >> 10) & (B_ - 1);
  int c = idx >> 12;
  float w = -__expf(tdec[d]);
  const ushort_t* kp = k + ((size_t)b * T_ + c * CH_) * D_ + d;
  const ushort_t* vp = v + ((size_t)b * T_ + c * CH_) * D_ + d;
  float num = 0.0f, den = 0.0f, q = -1e30f;
  for (int t0 = 0; t0 < CH_; t0 += 8) {
    float kt[8], vt[8];
    #pragma unroll
    for (int i = 0; i < 8; ++i) {
      size_t off = (size_t)(t0 + i) * D_;
      kt[i] = bf2f(kp[off]); vt[i] = bf2f(vp[off]);
    }
    #pragma unroll
    for (int i = 0; i < 8; ++i) {
      float kk = kt[i];
      float ms = fmaxf(q + w, kk);
      float e1 = __expf(q + w - ms), e2 = __expf(kk - ms);
      num = e1 * num + e2 * vt[i];
      den = e1 * den + e2;
      q = ms;
    }
  }
  cn[idx] = num; cd[idx] = den; cq[idx] = q;
}

__global__ __launch_bounds__(256) void wkv_part2(const float* __restrict__ cn,
                                                 const float* __restrict__ cd,
                                                 const float* __restrict__ cq,
                                                 const float* __restrict__ sn,
                                                 const float* __restrict__ sd,
                                                 const float* __restrict__ sq,
                                                 const float* __restrict__ tdec,
                                                 float* __restrict__ pn,
                                                 float* __restrict__ pd,
                                                 float* __restrict__ pq,
                                                 float* __restrict__ on,
                                                 float* __restrict__ od,
                                                 float* __restrict__ oq) {
  int idx = blockIdx.x * 256 + threadIdx.x;      // [b][d], 4096 threads
  int d = idx & (D_ - 1);
  float w = -__expf(tdec[d]);
  float wL = w * (float)CH_;
  float num = sn[idx], den = sd[idx], q = sq[idx];
  #pragma unroll 4
  for (int c = 0; c < NC_; ++c) {
    int j = (c << 12) + idx;
    pn[j] = num; pd[j] = den; pq[j] = q;        // exclusive prefix
    float m2 = cq[j];
    float qn = fmaxf(q + wL, m2);
    float e1 = __expf(q + wL - qn), e2 = __expf(m2 - qn);
    num = e1 * num + e2 * cn[j];
    den = e1 * den + e2 * cd[j];
    q = qn;
  }
  on[idx] = num; od[idx] = den; oq[idx] = q;
}

__global__ __launch_bounds__(256) void wkv_part3(const ushort_t* __restrict__ k,
                                                 const ushort_t* __restrict__ v,
                                                 const float* __restrict__ ra,
                                                 const float* __restrict__ rb,
                                                 const float* __restrict__ pn,
                                                 const float* __restrict__ pd,
                                                 const float* __restrict__ pq,
                                                 const float* __restrict__ tdec,
                                                 const float* __restrict__ tfirst,
                                                 ushort_t* __restrict__ rwkv) {
  int idx = blockIdx.x * 256 + threadIdx.x;      // [c][b][d]
  int d = idx & (D_ - 1);
  int b = (idx >> 10) & (B_ - 1);
  int c = idx >> 12;
  float w = -__expf(tdec[d]);
  float tf = tfirst[d];
  float num = pn[idx], den = pd[idx], q = pq[idx];
  size_t base = ((size_t)b * T_ + c * CH_) * D_ + d;
  const ushort_t* kp = k + base;
  const ushort_t* vp = v + base;
  const float* rap = ra + base;
  const float* rbp = rb + base;
  ushort_t* op = rwkv + base;
  for (int t0 = 0; t0 < CH_; t0 += 8) {
    float kt[8], vt[8], rt[8];
    #pragma unroll
    for (int i = 0; i < 8; ++i) {
      size_t off = (size_t)(t0 + i) * D_;
      kt[i] = bf2f(kp[off]); vt[i] = bf2f(vp[off]);
      rt[i] = 1.0f / (1.0f + __expf(-(rap[off] + rbp[off])));
    }
    #pragma unroll
    for (int i = 0; i < 8; ++i) {
      float kk = kt[i];
      float mo = fmaxf(q, kk + tf);
      float e1 = __expf(q - mo), e2 = __expf(kk + tf - mo);
      float o = (e1 * num + e2 * vt[i]) / (e1 * den + e2);
      __builtin_nontemporal_store(f2bf(rt[i] * o), op + (size_t)(t0 + i) * D_);
      float ms = fmaxf(q + w, kk);
      float e1s = __expf(q + w - ms), e2s = __expf(kk - ms);
      num = e1s * num + e2s * vt[i];
      den = e1s * den + e2s;
      q = ms;
    }
  }
}

// ============ 256x256 8-wave pipelined GEMM (8-phase fine interleave) ============
// EPI: 0 = split-K f32 (bz0->Cf, bz1->Cf2; kt0 = bz*ktn)
//      1 = relu(acc)^2 -> bf16 Ub
//      3 = z-batched: A+=z*M*D, Bt+=z*D*D; out bf16 Ub+z*M*D
template <int EPI>
__global__ __launch_bounds__(512, 2)
void gemm256(const ushort_t* __restrict__ A, const ushort_t* __restrict__ Bt,
             int N, int K, int ktn,
             float* __restrict__ Cf, float* __restrict__ Cf2,
             ushort_t* __restrict__ Ub) {
  __shared__ alignas(16) ushort_t sA[2][256 * 64];
  __shared__ alignas(16) ushort_t sB[2][256 * 64];
  const int tid = threadIdx.x;
  const int lane = tid & 63;
  const int wave = tid >> 6;
  const int wr = wave >> 2, wc = wave & 3;      // 2 x 4 wave grid
  const int l15 = lane & 15;
  const int kb = (lane >> 4) << 4;              // byte offset of k-group
  int bx, by, bz;
  xcd_swz(gridDim.x, gridDim.y, bx, by, bz);
  const int m0 = bx * 256, n0 = by * 256;
  const int kt0 = (EPI == 0) ? bz * ktn : 0;

  const ushort_t* Ause = A;
  const ushort_t* Buse = Bt;
  if (EPI == 3) {
    Ause = A + (size_t)bz * M_ * D_;
    Buse = Bt + (size_t)bz * D_ * D_;
  }
  const ushort_t* gA = Ause + (size_t)m0 * K + (size_t)kt0 * 64;
  const ushort_t* gB = Buse + (size_t)n0 * K + (size_t)kt0 * 64;

  const int sr = tid >> 3;                      // 0..63
  const int sc8 = (tid & 7) ^ (sr & 7);         // pre-swizzled col-8 group
  const int scb = (tid & 7) * 16;               // linear LDS byte col

  auto stage = [&](int dbuf, int kt, int h) {
    const ushort_t* g = (h < 2) ? gA : gB;
    ushort_t* sb = (h < 2) ? sA[dbuf] : sB[dbuf];
    int rbase = (h & 1) * 128;
    #pragma unroll
    for (int i = 0; i < 2; ++i) {
      int row = rbase + i * 64 + sr;
      gl_lds16(g + (size_t)row * K + (size_t)kt * 64 + sc8 * 8,
               (char*)sb + row * 128 + scb);
    }
  };

  auto ld = [&](const ushort_t* sbuf, int row, int s5) -> short8 {
    int cb = ((s5 << 6) + kb) ^ ((row & 7) << 4);
    return *(const short8*)((const char*)sbuf + row * 128 + cb);
  };

  f32x4 acc[8][4] = {};

  stage(0, 0, 0); stage(0, 0, 1); stage(0, 0, 2); stage(0, 0, 3);

  for (int t = 0; t < ktn; ++t) {
    const int cur = t & 1, nxt = cur ^ 1;
    const bool more = (t + 1 < ktn);
    if (more) { stage(nxt, t + 1, 0); stage(nxt, t + 1, 1); }
    if (more) asm volatile("s_waitcnt vmcnt(4)" ::: "memory");
    else      asm volatile("s_waitcnt vmcnt(0)" ::: "memory");
    __builtin_amdgcn_s_barrier();

    const ushort_t* curA = sA[cur];
    const ushort_t* curB = sB[cur];
    short8 bfr[4][2];

#define G256_MFMA16(MI0, A00, A01, A10, A11)                                  \
    __builtin_amdgcn_s_setprio(1);                                            \
    _Pragma("unroll")                                                         \
    for (int ni = 0; ni < 4; ++ni) {                                          \
      acc[MI0][ni] = __builtin_amdgcn_mfma_f32_16x16x32_bf16(                 \
          A00, bfr[ni][0], acc[MI0][ni], 0, 0, 0);                            \
      acc[MI0][ni] = __builtin_amdgcn_mfma_f32_16x16x32_bf16(                 \
          A01, bfr[ni][1], acc[MI0][ni], 0, 0, 0);                            \
      acc[MI0 + 1][ni] = __builtin_amdgcn_mfma_f32_16x16x32_bf16(             \
          A10, bfr[ni][0], acc[MI0 + 1][ni], 0, 0, 0);                        \
      acc[MI0 + 1][ni] = __builtin_amdgcn_mfma_f32_16x16x32_bf16(             \
          A11, bfr[ni][1], acc[MI0 + 1][ni], 0, 0, 0);                        \
    }                                                                         \
    __builtin_amdgcn_s_setprio(0);

#define G256_SYNC_IN()                                                        \
    asm volatile("" ::: "memory");                                            \
    __builtin_amdgcn_s_barrier();                                             \
    asm volatile("s_waitcnt lgkmcnt(0)" ::: "memory");                        \
    __builtin_amdgcn_sched_barrier(0);

#define G256_SYNC_OUT()                                                       \
    asm volatile("" ::: "memory");                                            \
    __builtin_amdgcn_s_barrier();

    {   // phase 0: all B frags + A(0,1); stage B-half0 of t+1
      #pragma unroll
      for (int ni = 0; ni < 4; ++ni)
        #pragma unroll
        for (int s = 0; s < 2; ++s)
          bfr[ni][s] = ld(curB, wc * 64 + ni * 16 + l15, s);
      short8 a00 = ld(curA, wr * 128 + 0 * 16 + l15, 0);
      short8 a01 = ld(curA, wr * 128 + 0 * 16 + l15, 1);
      short8 a10 = ld(curA, wr * 128 + 1 * 16 + l15, 0);
      short8 a11 = ld(curA, wr * 128 + 1 * 16 + l15, 1);
      if (more) stage(nxt, t + 1, 2);
      G256_SYNC_IN();
      G256_MFMA16(0, a00, a01, a10, a11);
      G256_SYNC_OUT();
    }
    {   // phase 1: A(2,3); stage B-half1 of t+1
      short8 a00 = ld(curA, wr * 128 + 2 * 16 + l15, 0);
      short8 a01 = ld(curA, wr * 128 + 2 * 16 + l15, 1);
      short8 a10 = ld(curA, wr * 128 + 3 * 16 + l15, 0);
      short8 a11 = ld(curA, wr * 128 + 3 * 16 + l15, 1);
      if (more) stage(nxt, t + 1, 3);
      G256_SYNC_IN();
      G256_MFMA16(2, a00, a01, a10, a11);
      G256_SYNC_OUT();
    }
    {   // phase 2: A(4,5)
      short8 a00 = ld(curA, wr * 128 + 4 * 16 + l15, 0);
      short8 a01 = ld(curA, wr * 128 + 4 * 16 + l15, 1);
      short8 a10 = ld(curA, wr * 128 + 5 * 16 + l15, 0);
      short8 a11 = ld(curA, wr * 128 + 5 * 16 + l15, 1);
      G256_SYNC_IN();
      G256_MFMA16(4, a00, a01, a10, a11);
      G256_SYNC_OUT();
    }
    {   // phase 3: A(6,7)
      short8 a00 = ld(curA, wr * 128 + 6 * 16 + l15, 0);
      short8 a01 = ld(curA, wr * 128 + 6 * 16 + l15, 1);
      short8 a10 = ld(curA, wr * 128 + 7 * 16 + l15, 0);
      short8 a11 = ld(curA, wr * 128 + 7 * 16 + l15, 1);
      G256_SYNC_IN();
      G256_MFMA16(6, a00, a01, a10, a11);
      G256_SYNC_OUT();
    }
  }

  float* cfp = (EPI == 0 && bz) ? Cf2 : Cf;
  ushort_t* ub = Ub;
  if (EPI == 3) ub = Ub + (size_t)bz * M_ * D_;
  #pragma unroll
  for (int mi = 0; mi < 8; ++mi)
    #pragma unroll
    for (int ni = 0; ni < 4; ++ni)
      #pragma unroll
      for (int j = 0; j < 4; ++j) {
        int row = m0 + wr * 128 + mi * 16 + ((lane >> 4) << 2) + j;
        int col = n0 + wc * 64 + ni * 16 + l15;
        size_t idx = (size_t)row * N + col;
        float v = acc[mi][ni][j];
        if (EPI == 0) {
          __builtin_nontemporal_store(v, cfp + idx);
        } else if (EPI == 1) {
          float tt = v > 0.0f ? v : 0.0f;
          __builtin_nontemporal_store(f2bf(tt * tt), ub + idx);
        } else if (EPI == 3) {
          __builtin_nontemporal_store(f2bf(v), ub + idx);
        }
      }
}

// ============ 128x256 8-wave pipelined GEMM (D-output GEMMs), B [N][K] ==========
// N fixed 1024. EPI: 2 = Cf = X + acc
//                  4 = Cf = X2 + sigmoid(acc) * (X + Xb)
template <int EPI>
__global__ __launch_bounds__(512, 2)
void gemmB(const ushort_t* __restrict__ A, const ushort_t* __restrict__ Bt,
           int K, int ktn,
           float* __restrict__ Cf,
           const float* __restrict__ X, const float* __restrict__ X2,
           const float* __restrict__ Xb) {
  __shared__ alignas(16) ushort_t sA[2][128 * 64];
  __shared__ alignas(16) ushort_t sB[2][256 * 64];
  const int tid = threadIdx.x;
  const int lane = tid & 63;
  const int wave = tid >> 6;
  const int wr = wave >> 2, wc = wave & 3;      // 2 x 4 wave grid (64-row, 64-col)
  const int l15 = lane & 15;
  const int kb = (lane >> 4) << 4;
  int bx, by, zid;
  xcd_swz(gridDim.x, gridDim.y, bx, by, zid);
  const int m0 = bx * 128, n0 = by * 256;

  const ushort_t* gA = A + (size_t)m0 * K;
  const ushort_t* gB = Bt + (size_t)n0 * K;

  const int sr = tid >> 3;
  const int sc8 = (tid & 7) ^ (sr & 7);
  const int scb = (tid & 7) * 16;

  // h: 0,1 = A 64-row halves (1 round each); 2,3 = B 128-row halves (2 rounds)
  auto stage = [&](int dbuf, int kt, int h) {
    if (h < 2) {
      int row = h * 64 + sr;
      gl_lds16(gA + (size_t)row * K + (size_t)kt * 64 + sc8 * 8,
               (char*)sA[dbuf] + row * 128 + scb);
    } else {
      int rbase = (h - 2) * 128;
      #pragma unroll
      for (int i = 0; i < 2; ++i) {
        int row = rbase + i * 64 + sr;
        gl_lds16(gB + (size_t)row * K + (size_t)kt * 64 + sc8 * 8,
                 (char*)sB[dbuf] + row * 128 + scb);
      }
    }
  };

  auto ld = [&](const ushort_t* sbuf, int row, int s5) -> short8 {
    int cb = ((s5 << 6) + kb) ^ ((row & 7) << 4);
    return *(const short8*)((const char*)sbuf + row * 128 + cb);
  };

  f32x4 acc[4][4] = {};

  stage(0, 0, 0); stage(0, 0, 1); stage(0, 0, 2); stage(0, 0, 3);

  for (int t = 0; t < ktn; ++t) {
    const int cur = t & 1, nxt = cur ^ 1;
    const bool more = (t + 1 < ktn);
    if (more) {
      stage(nxt, t + 1, 0); stage(nxt, t + 1, 1);
      stage(nxt, t + 1, 2); stage(nxt, t + 1, 3);
    }
    if (more) asm volatile("s_waitcnt vmcnt(6)" ::: "memory");
    else      asm volatile("s_waitcnt vmcnt(0)" ::: "memory");
    __builtin_amdgcn_s_barrier();

    const ushort_t* curA = sA[cur];
    const ushort_t* curB = sB[cur];

    #pragma unroll
    for (int s = 0; s < 2; ++s) {   // 2 phases: one per k-half
      short8 av[4], bv[4];
      #pragma unroll
      for (int i = 0; i < 4; ++i) av[i] = ld(curA, wr * 64 + i * 16 + l15, s);
      #pragma unroll
      for (int i = 0; i < 4; ++i) bv[i] = ld(curB, wc * 64 + i * 16 + l15, s);
      asm volatile("" ::: "memory");
      __builtin_amdgcn_s_barrier();
      asm volatile("s_waitcnt lgkmcnt(0)" ::: "memory");
      __builtin_amdgcn_sched_barrier(0);
      __builtin_amdgcn_s_setprio(1);
      #pragma unroll
      for (int mi = 0; mi < 4; ++mi)
        #pragma unroll
        for (int ni = 0; ni < 4; ++ni)
          acc[mi][ni] = __builtin_amdgcn_mfma_f32_16x16x32_bf16(
              av[mi], bv[ni], acc[mi][ni], 0, 0, 0);
      __builtin_amdgcn_s_setprio(0);
      asm volatile("" ::: "memory");
      __builtin_amdgcn_s_barrier();
    }
  }

  #pragma unroll
  for (int mi = 0; mi < 4; ++mi)
    #pragma unroll
    for (int ni = 0; ni < 4; ++ni)
      #pragma unroll
      for (int j = 0; j < 4; ++j) {
        int row = m0 + wr * 64 + mi * 16 + ((lane >> 4) << 2) + j;
        int col = n0 + wc * 64 + ni * 16 + l15;
        size_t idx = (size_t)row * D_ + col;
        float v = acc[mi][ni][j];
        if (EPI == 2) {
          __builtin_nontemporal_store(X[idx] + v, Cf + idx);
        } else if (EPI == 4) {
          float s = 1.0f / (1.0f + __expf(-v));
          __builtin_nontemporal_store(X2[idx] + s * (X[idx] + Xb[idx]), Cf + idx);
        }
      }
}

// ---------------- launcher ----------------
extern "C" void kernel_launch(void* const* d_in, const int* in_sizes, int n_in,
                              void* d_out, int out_size, void* d_ws, size_t ws_size,
                              hipStream_t stream) {
  const float* x      = (const float*)d_in[0];
  const float* s_cm   = (const float*)d_in[1];
  const float* s_tm   = (const float*)d_in[2];
  const float* s_num  = (const float*)d_in[3];
  const float* s_den  = (const float*)d_in[4];
  const float* s_q    = (const float*)d_in[5];
  const float* ln1_g  = (const float*)d_in[6];
  const float* ln1_b  = (const float*)d_in[7];
  const float* ln2_g  = (const float*)d_in[8];
  const float* ln2_b  = (const float*)d_in[9];
  const float* tmk    = (const float*)d_in[10];
  const float* tmv    = (const float*)d_in[11];
  const float* tmr    = (const float*)d_in[12];
  const float* tm_kw  = (const float*)d_in[13];
  const float* tm_vw  = (const float*)d_in[14];
  const float* tm_rw  = (const float*)d_in[15];
  const float* tdec   = (const float*)d_in[16];
  const float* tfirst = (const float*)d_in[17];
  const float* out_w  = (const float*)d_in[18];
  const float* cmk    = (const float*)d_in[19];
  const float* cmr    = (const float*)d_in[20];
  const float* cm_kw  = (const float*)d_in[21];
  const float* cm_vw  = (const float*)d_in[22];
  const float* cm_rw  = (const float*)d_in[23];

  float* out   = (float*)d_out;
  float* o_x   = out;
  float* o_h2l = out + (size_t)M_ * D_;
  float* o_hl  = o_h2l + B_ * D_;
  float* o_num = o_hl + B_ * D_;
  float* o_den = o_num + B_ * D_;
  float* o_q   = o_den + B_ * D_;

  char* W = (char*)d_ws;
  const size_t MB = 1024 * 1024;
  ushort_t* w_tmk = (ushort_t*)(W + 0 * MB);   // [w_tmk | w_tmv contiguous]
  ushort_t* w_tmv = (ushort_t*)(W + 2 * MB);
  ushort_t* w_tmr = (ushort_t*)(W + 4 * MB);
  ushort_t* w_out = (ushort_t*)(W + 6 * MB);
  ushort_t* w_cmk = (ushort_t*)(W + 8 * MB);
  ushort_t* w_cmv = (ushort_t*)(W + 16 * MB);
  ushort_t* w_cmr = (ushort_t*)(W + 24 * MB);
  // scan scratch 26..29MB
  float* cn = (float*)(W + 26 * MB + 0 * 512 * 1024);
  float* cd = (float*)(W + 26 * MB + 1 * 512 * 1024);
  float* cq = (float*)(W + 26 * MB + 2 * 512 * 1024);
  float* pn = (float*)(W + 26 * MB + 3 * 512 * 1024);
  float* pd = (float*)(W + 26 * MB + 4 * 512 * 1024);
  float* pq = (float*)(W + 26 * MB + 5 * 512 * 1024);
  ushort_t* xk    = (ushort_t*)(W + 32 * MB);  // [xk | xv contiguous M*D bf16]
  ushort_t* xv    = (ushort_t*)(W + 48 * MB);
  ushort_t* xr    = (ushort_t*)(W + 64 * MB);
  ushort_t* kbuf  = (ushort_t*)(W + 80 * MB);  // [kbuf | vbuf contiguous M*D bf16]
  ushort_t* vbuf  = (ushort_t*)(W + 96 * MB);
  ushort_t* kk    = (ushort_t*)(W + 128 * MB); // bf16 M*F (64MB)
  float*    ra    = (float*)(W + 32 * MB);     // f32 32MB: xk+xv region (dead after k+v GEMM)
  float*    rb    = (float*)(W + 128 * MB);    // f32 32MB: kk region (dead until cm_kw)
  float*    kv_a  = (float*)(W + 64 * MB);     // f32 32MB (xr+kbuf, dead after out_w/scan)
  float*    kv_b  = (float*)(W + 96 * MB);     // f32 32MB (vbuf+, dead after scan)
  ushort_t* rwkv  = xr;               // reuse (xr dead after r GEMM)
  ushort_t* xk2   = xk;               // reuse (after part3)
  ushort_t* xr2   = xv;               // reuse

  dim3 tb(32, 8);
  // weight convert + transpose (bf16, [N][K]); 5 DxD batched + the two F weights
  tconv5<<<dim3(D_/32, D_/32, 5), tb, 0, stream>>>(tm_kw, tm_vw, tm_rw, out_w, cm_rw,
                                                   w_tmk, w_tmv, w_tmr, w_out, w_cmr);
  tconv<<<dim3(F_/32, D_/32), tb, 0, stream>>>(cm_kw, w_cmk, D_, F_);
  tconv<<<dim3(D_/32, F_/32), tb, 0, stream>>>(cm_vw, w_cmv, F_, D_);

  // time-mix path: fused LN1 + token-shift mix -> xk,xv,xr (bf16)
  ln_mix<3><<<M_, 256, 0, stream>>>(x, s_tm, ln1_g, ln1_b, tmk, tmv, tmr,
                                    xk, xv, xr, o_hl);
  // k+v batched (z=0 k, z=1 v): grid 256 = 1 exact round -> bf16 kbuf/vbuf
  gemm256<3><<<dim3(M_/256, D_/256, 2), 512, 0, stream>>>(
      xk, w_tmk, D_, D_, D_/64, nullptr, nullptr, kbuf);
  // r split-K=2: grid 256 = 1 exact round -> f32 partials ra, rb
  gemm256<0><<<dim3(M_/256, D_/256, 2), 512, 0, stream>>>(
      xr, w_tmr, D_, D_, D_/128, ra, rb, nullptr);

  // chunked parallel WKV scan (bf16 k/v; r = sigmoid(ra+rb) in part3)
  wkv_part1<<<(NC_ * B_ * D_) / 256, 256, 0, stream>>>(kbuf, vbuf, tdec, cn, cd, cq);
  wkv_part2<<<(B_ * D_) / 256, 256, 0, stream>>>(cn, cd, cq, s_num, s_den, s_q, tdec,
                                                 pn, pd, pq, o_num, o_den, o_q);
  wkv_part3<<<(NC_ * B_ * D_) / 256, 256, 0, stream>>>(kbuf, vbuf, ra, rb, pn, pd, pq,
                                                       tdec, tfirst, rwkv);

  // out_w + residual: o_x = x + (r*wkv)@out_w   (256 blocks = 1 exact round)
  gemmB<2><<<dim3(M_/128, D_/256, 1), 512, 0, stream>>>(
      rwkv, w_out, D_, D_/64, o_x, x, nullptr, nullptr);

  // channel-mix path: fused LN2 + mix -> xk2, xr2
  ln_mix<2><<<M_, 256, 0, stream>>>(o_x, s_cm, ln2_g, ln2_b, cmk, nullptr, cmr,
                                    xk2, nullptr, xr2, o_h2l);
  // cm_kw: [M,D]@[D,F] -> relu^2 -> bf16 kk   (512 blocks = 2 exact rounds)
  gemm256<1><<<dim3(M_/256, F_/256, 1), 512, 0, stream>>>(
      xk2, w_cmk, F_, D_, D_/64, nullptr, nullptr, kk);
  // cm_vw: [M,F]@[F,D] split-K=2 -> kv_a + kv_b (256 blocks = 1 exact round)
  gemm256<0><<<dim3(M_/256, D_/256, 2), 512, 0, stream>>>(
      kk, w_cmv, D_, F_, F_/128, kv_a, kv_b, nullptr);
  // cm_rw + gate + residual: o_x = o_x + sigmoid(acc)*(kv_a+kv_b)  (256 blocks)
  gemmB<4><<<dim3(M_/128, D_/256, 1), 512, 0, stream>>>(
      xr2, w_cmr, D_, D_/64, o_x, kv_a, o_x, kv_b);
}

// Round 10
// 392.443 us; speedup vs baseline: 1.2444x; 1.2444x over previous
//
#include <hip/hip_runtime.h>

typedef unsigned short ushort_t;
typedef __attribute__((ext_vector_type(8))) short short8;
typedef __attribute__((ext_vector_type(4))) float f32x4;

#define B_ 4
#define T_ 2048
#define D_ 1024
#define F_ 4096
#define M_ (B_*T_)
#define CH_ 64
#define NC_ (T_/CH_)   // 32 chunks

#define AS1 __attribute__((address_space(1)))
#define AS3 __attribute__((address_space(3)))

__device__ __forceinline__ ushort_t f2bf(float f) {
  union { float f; unsigned u; } a; a.f = f;
  unsigned r = a.u + 0x7FFFu + ((a.u >> 16) & 1u);
  return (ushort_t)(r >> 16);
}

__device__ __forceinline__ float bf2f(ushort_t u) {
  union { unsigned u; float f; } a; a.u = ((unsigned)u) << 16;
  return a.f;
}

__device__ __forceinline__ void gl_lds16(const void* g, void* l) {
  __builtin_amdgcn_global_load_lds((AS1 void*)(__UINTPTR_TYPE__)g,
                                   (AS3 void*)l, 16, 0, 0);
}

// XCD-chunked bijective swizzle (T1) + 4x4 block supertiles inside each XCD
// chunk (keeps A-panels x B-panels working set ~4MB = L2-resident).
// Valid for gy == 4 or gy % 4 == 0, nwg % 8 == 0.
__device__ __forceinline__ void xcd_swz(int gx, int gy, int& bx, int& by, int& bz) {
  int lid = blockIdx.x + gx * (blockIdx.y + gy * blockIdx.z);
  int nwg = gx * gy * gridDim.z;
  int cpx = nwg >> 3;
  int L = (lid & 7) * cpx + (lid >> 3);
  int gy4 = (gy >= 4) ? (gy >> 2) : 1;
  by = (L & 3) + 4 * ((L >> 4) % gy4);
  int bxz = ((L >> 2) & 3) + 4 * (L / (4 * gy));
  bx = bxz % gx;
  bz = bxz / gx;
}

// ---------------- transpose + f32->bf16 convert: Wt[n][k] = W[k][n] ----------------
__global__ __launch_bounds__(256) void tconv(const float* __restrict__ W,
                                             ushort_t* __restrict__ Wt,
                                             int K, int N) {
  __shared__ float tile[32][33];
  int tx = threadIdx.x, ty = threadIdx.y;
  int n0 = blockIdx.x * 32, k0 = blockIdx.y * 32;
  #pragma unroll
  for (int i = 0; i < 32; i += 8)
    tile[ty + i][tx] = W[(size_t)(k0 + ty + i) * N + n0 + tx];
  __syncthreads();
  #pragma unroll
  for (int i = 0; i < 32; i += 8)
    Wt[(size_t)(n0 + ty + i) * K + k0 + tx] = f2bf(tile[tx][ty + i]);
}

// batched D x D transposes (z selects src/dst)
__global__ __launch_bounds__(256) void tconv5(const float* __restrict__ s0,
                                              const float* __restrict__ s1,
                                              const float* __restrict__ s2,
                                              const float* __restrict__ s3,
                                              const float* __restrict__ s4,
                                              ushort_t* __restrict__ d0,
                                              ushort_t* __restrict__ d1,
                                              ushort_t* __restrict__ d2,
                                              ushort_t* __restrict__ d3,
                                              ushort_t* __restrict__ d4) {
  __shared__ float tile[32][33];
  int z = blockIdx.z;
  const float* W = (z == 0) ? s0 : (z == 1) ? s1 : (z == 2) ? s2 : (z == 3) ? s3 : s4;
  ushort_t* Wt   = (z == 0) ? d0 : (z == 1) ? d1 : (z == 2) ? d2 : (z == 3) ? d3 : d4;
  int tx = threadIdx.x, ty = threadIdx.y;
  int n0 = blockIdx.x * 32, k0 = blockIdx.y * 32;
  #pragma unroll
  for (int i = 0; i < 32; i += 8)
    tile[ty + i][tx] = W[(size_t)(k0 + ty + i) * D_ + n0 + tx];
  __syncthreads();
  #pragma unroll
  for (int i = 0; i < 32; i += 8)
    Wt[(size_t)(n0 + ty + i) * D_ + k0 + tx] = f2bf(tile[tx][ty + i]);
}

// ---------------- fused LayerNorm + token-shift mix ----------------
#define MIX1(c, p, f) f2bf((c) * (f) + (p) * (1.0f - (f)))

template <int NOUT>
__global__ __launch_bounds__(256)
void ln_mix(const float* __restrict__ xin, const float* __restrict__ st,
            const float* __restrict__ g, const float* __restrict__ bb,
            const float* __restrict__ mk, const float* __restrict__ mv,
            const float* __restrict__ mr,
            ushort_t* __restrict__ ok, ushort_t* __restrict__ ov,
            ushort_t* __restrict__ orr, float* __restrict__ last) {
  int row = blockIdx.x;                  // b*T + t
  int t = row & (T_ - 1);
  int b = row >> 11;
  int tid = threadIdx.x;
  const bool pln = (t != 0);
  float4 vc = ((const float4*)(xin + (size_t)row * D_))[tid];
  float4 vp = pln ? ((const float4*)(xin + (size_t)(row - 1) * D_))[tid]
                  : ((const float4*)(st + (size_t)b * D_))[tid];
  float s0 = vc.x + vc.y + vc.z + vc.w;
  float s1 = vc.x * vc.x + vc.y * vc.y + vc.z * vc.z + vc.w * vc.w;
  float s2 = vp.x + vp.y + vp.z + vp.w;
  float s3 = vp.x * vp.x + vp.y * vp.y + vp.z * vp.z + vp.w * vp.w;
  #pragma unroll
  for (int o = 32; o > 0; o >>= 1) {
    s0 += __shfl_down(s0, o); s1 += __shfl_down(s1, o);
    s2 += __shfl_down(s2, o); s3 += __shfl_down(s3, o);
  }
  __shared__ float red[4][4];
  if ((tid & 63) == 0) {
    int w = tid >> 6;
    red[w][0] = s0; red[w][1] = s1; red[w][2] = s2; red[w][3] = s3;
  }
  __syncthreads();
  float cs0 = red[0][0] + red[1][0] + red[2][0] + red[3][0];
  float cs1 = red[0][1] + red[1][1] + red[2][1] + red[3][1];
  float ps0 = red[0][2] + red[1][2] + red[2][2] + red[3][2];
  float ps1 = red[0][3] + red[1][3] + red[2][3] + red[3][3];

  float mu = cs0 * (1.0f / D_);
  float rs = rsqrtf(cs1 * (1.0f / D_) - mu * mu + 1e-3f);
  float4 gv = ((const float4*)g)[tid];
  float4 bv = ((const float4*)bb)[tid];
  float hc[4], hp[4];
  hc[0] = (vc.x - mu) * rs * gv.x + bv.x;
  hc[1] = (vc.y - mu) * rs * gv.y + bv.y;
  hc[2] = (vc.z - mu) * rs * gv.z + bv.z;
  hc[3] = (vc.w - mu) * rs * gv.w + bv.w;
  if (pln) {
    float mup = ps0 * (1.0f / D_);
    float rsp = rsqrtf(ps1 * (1.0f / D_) - mup * mup + 1e-3f);
    hp[0] = (vp.x - mup) * rsp * gv.x + bv.x;
    hp[1] = (vp.y - mup) * rsp * gv.y + bv.y;
    hp[2] = (vp.z - mup) * rsp * gv.z + bv.z;
    hp[3] = (vp.w - mup) * rsp * gv.w + bv.w;
  } else {
    hp[0] = vp.x; hp[1] = vp.y; hp[2] = vp.z; hp[3] = vp.w;
  }

  size_t qi = (size_t)row * 256 + tid;   // ushort4 index
  float4 k4 = ((const float4*)mk)[tid];
  float4 r4 = ((const float4*)mr)[tid];
  ushort4 o4;
  o4.x = MIX1(hc[0], hp[0], k4.x); o4.y = MIX1(hc[1], hp[1], k4.y);
  o4.z = MIX1(hc[2], hp[2], k4.z); o4.w = MIX1(hc[3], hp[3], k4.w);
  ((ushort4*)ok)[qi] = o4;
  if (NOUT == 3) {
    float4 v4 = ((const float4*)mv)[tid];
    o4.x = MIX1(hc[0], hp[0], v4.x); o4.y = MIX1(hc[1], hp[1], v4.y);
    o4.z = MIX1(hc[2], hp[2], v4.z); o4.w = MIX1(hc[3], hp[3], v4.w);
    ((ushort4*)ov)[qi] = o4;
  }
  o4.x = MIX1(hc[0], hp[0], r4.x); o4.y = MIX1(hc[1], hp[1], r4.y);
  o4.z = MIX1(hc[2], hp[2], r4.z); o4.w = MIX1(hc[3], hp[3], r4.w);
  ((ushort4*)orr)[qi] = o4;

  if (t == T_ - 1) {
    float4 h4; h4.x = hc[0]; h4.y = hc[1]; h4.z = hc[2]; h4.w = hc[3];
    ((float4*)(last + (size_t)b * D_))[tid] = h4;
  }
}

// ---------------- WKV chunked parallel scan (bf16 k/v; r from f32 partials) -------
__global__ __launch_bounds__(256) void wkv_part1(const ushort_t* __restrict__ k,
                                                 const ushort_t* __restrict__ v,
                                                 const float* __restrict__ tdec,
                                                 float* __restrict__ cn,
                                                 float* __restrict__ cd,
                                                 float* __restrict__ cq) {
  int idx = blockIdx.x * 256 + threadIdx.x;      // [c][b][d]
  int d = idx & (D_ - 1);
  int b = (idx >> 10) & (B_ - 1);
  int c = idx >> 12;
  float w = -__expf(tdec[d]);
  const ushort_t* kp = k + ((size_t)b * T_ + c * CH_) * D_ + d;
  const ushort_t* vp = v + ((size_t)b * T_ + c * CH_) * D_ + d;
  float num = 0.0f, den = 0.0f, q = -1e30f;
  for (int t0 = 0; t0 < CH_; t0 += 8) {
    float kt[8], vt[8];
    #pragma unroll
    for (int i = 0; i < 8; ++i) {
      size_t off = (size_t)(t0 + i) * D_;
      kt[i] = bf2f(kp[off]); vt[i] = bf2f(vp[off]);
    }
    #pragma unroll
    for (int i = 0; i < 8; ++i) {
      float kk = kt[i];
      float ms = fmaxf(q + w, kk);
      float e1 = __expf(q + w - ms), e2 = __expf(kk - ms);
      num = e1 * num + e2 * vt[i];
      den = e1 * den + e2;
      q = ms;
    }
  }
  cn[idx] = num; cd[idx] = den; cq[idx] = q;
}

__global__ __launch_bounds__(256) void wkv_part2(const float* __restrict__ cn,
                                                 const float* __restrict__ cd,
                                                 const float* __restrict__ cq,
                                                 const float* __restrict__ sn,
                                                 const float* __restrict__ sd,
                                                 const float* __restrict__ sq,
                                                 const float* __restrict__ tdec,
                                                 float* __restrict__ pn,
                                                 float* __restrict__ pd,
                                                 float* __restrict__ pq,
                                                 float* __restrict__ on,
                                                 float* __restrict__ od,
                                                 float* __restrict__ oq) {
  int idx = blockIdx.x * 256 + threadIdx.x;      // [b][d], 4096 threads
  int d = idx & (D_ - 1);
  float w = -__expf(tdec[d]);
  float wL = w * (float)CH_;
  float num = sn[idx], den = sd[idx], q = sq[idx];
  #pragma unroll 4
  for (int c = 0; c < NC_; ++c) {
    int j = (c << 12) + idx;
    pn[j] = num; pd[j] = den; pq[j] = q;        // exclusive prefix
    float m2 = cq[j];
    float qn = fmaxf(q + wL, m2);
    float e1 = __expf(q + wL - qn), e2 = __expf(m2 - qn);
    num = e1 * num + e2 * cn[j];
    den = e1 * den + e2 * cd[j];
    q = qn;
  }
  on[idx] = num; od[idx] = den; oq[idx] = q;
}

__global__ __launch_bounds__(256) void wkv_part3(const ushort_t* __restrict__ k,
                                                 const ushort_t* __restrict__ v,
                                                 const float* __restrict__ ra,
                                                 const float* __restrict__ rb,
                                                 const float* __restrict__ pn,
                                                 const float* __restrict__ pd,
                                                 const float* __restrict__ pq,
                                                 const float* __restrict__ tdec,
                                                 const float* __restrict__ tfirst,
                                                 ushort_t* __restrict__ rwkv) {
  int idx = blockIdx.x * 256 + threadIdx.x;      // [c][b][d]
  int d = idx & (D_ - 1);
  int b = (idx >> 10) & (B_ - 1);
  int c = idx >> 12;
  float w = -__expf(tdec[d]);
  float tf = tfirst[d];
  float num = pn[idx], den = pd[idx], q = pq[idx];
  size_t base = ((size_t)b * T_ + c * CH_) * D_ + d;
  const ushort_t* kp = k + base;
  const ushort_t* vp = v + base;
  const float* rap = ra + base;
  const float* rbp = rb + base;
  ushort_t* op = rwkv + base;
  for (int t0 = 0; t0 < CH_; t0 += 8) {
    float kt[8], vt[8], rt[8];
    #pragma unroll
    for (int i = 0; i < 8; ++i) {
      size_t off = (size_t)(t0 + i) * D_;
      kt[i] = bf2f(kp[off]); vt[i] = bf2f(vp[off]);
      rt[i] = 1.0f / (1.0f + __expf(-(rap[off] + rbp[off])));
    }
    #pragma unroll
    for (int i = 0; i < 8; ++i) {
      float kk = kt[i];
      float mo = fmaxf(q, kk + tf);
      float e1 = __expf(q - mo), e2 = __expf(kk + tf - mo);
      float o = (e1 * num + e2 * vt[i]) / (e1 * den + e2);
      op[(size_t)(t0 + i) * D_] = f2bf(rt[i] * o);
      float ms = fmaxf(q + w, kk);
      float e1s = __expf(q + w - ms), e2s = __expf(kk - ms);
      num = e1s * num + e2s * vt[i];
      den = e1s * den + e2s;
      q = ms;
    }
  }
}

// ============ 256x256 8-wave pipelined GEMM (8-phase fine interleave) ============
// EPI: 0 = split-K f32 (bz0->Cf, bz1->Cf2; kt0 = bz*ktn)
//      1 = relu(acc)^2 -> bf16 Ub
//      3 = z-batched: A+=z*M*D, Bt+=z*D*D; out bf16 Ub+z*M*D
template <int EPI>
__global__ __launch_bounds__(512, 2)
void gemm256(const ushort_t* __restrict__ A, const ushort_t* __restrict__ Bt,
             int N, int K, int ktn,
             float* __restrict__ Cf, float* __restrict__ Cf2,
             ushort_t* __restrict__ Ub) {
  __shared__ alignas(16) ushort_t sA[2][256 * 64];
  __shared__ alignas(16) ushort_t sB[2][256 * 64];
  const int tid = threadIdx.x;
  const int lane = tid & 63;
  const int wave = tid >> 6;
  const int wr = wave >> 2, wc = wave & 3;      // 2 x 4 wave grid
  const int l15 = lane & 15;
  const int kb = (lane >> 4) << 4;              // byte offset of k-group
  int bx, by, bz;
  xcd_swz(gridDim.x, gridDim.y, bx, by, bz);
  const int m0 = bx * 256, n0 = by * 256;
  const int kt0 = (EPI == 0) ? bz * ktn : 0;

  const ushort_t* Ause = A;
  const ushort_t* Buse = Bt;
  if (EPI == 3) {
    Ause = A + (size_t)bz * M_ * D_;
    Buse = Bt + (size_t)bz * D_ * D_;
  }
  const ushort_t* gA = Ause + (size_t)m0 * K + (size_t)kt0 * 64;
  const ushort_t* gB = Buse + (size_t)n0 * K + (size_t)kt0 * 64;

  const int sr = tid >> 3;                      // 0..63
  const int sc8 = (tid & 7) ^ (sr & 7);         // pre-swizzled col-8 group
  const int scb = (tid & 7) * 16;               // linear LDS byte col

  auto stage = [&](int dbuf, int kt, int h) {
    const ushort_t* g = (h < 2) ? gA : gB;
    ushort_t* sb = (h < 2) ? sA[dbuf] : sB[dbuf];
    int rbase = (h & 1) * 128;
    #pragma unroll
    for (int i = 0; i < 2; ++i) {
      int row = rbase + i * 64 + sr;
      gl_lds16(g + (size_t)row * K + (size_t)kt * 64 + sc8 * 8,
               (char*)sb + row * 128 + scb);
    }
  };

  auto ld = [&](const ushort_t* sbuf, int row, int s5) -> short8 {
    int cb = ((s5 << 6) + kb) ^ ((row & 7) << 4);
    return *(const short8*)((const char*)sbuf + row * 128 + cb);
  };

  f32x4 acc[8][4] = {};

  stage(0, 0, 0); stage(0, 0, 1); stage(0, 0, 2); stage(0, 0, 3);

  for (int t = 0; t < ktn; ++t) {
    const int cur = t & 1, nxt = cur ^ 1;
    const bool more = (t + 1 < ktn);
    if (more) { stage(nxt, t + 1, 0); stage(nxt, t + 1, 1); }
    if (more) asm volatile("s_waitcnt vmcnt(4)" ::: "memory");
    else      asm volatile("s_waitcnt vmcnt(0)" ::: "memory");
    __builtin_amdgcn_s_barrier();

    const ushort_t* curA = sA[cur];
    const ushort_t* curB = sB[cur];
    short8 bfr[4][2];

#define G256_MFMA16(MI0, A00, A01, A10, A11)                                  \
    __builtin_amdgcn_s_setprio(1);                                            \
    _Pragma("unroll")                                                         \
    for (int ni = 0; ni < 4; ++ni) {                                          \
      acc[MI0][ni] = __builtin_amdgcn_mfma_f32_16x16x32_bf16(                 \
          A00, bfr[ni][0], acc[MI0][ni], 0, 0, 0);                            \
      acc[MI0][ni] = __builtin_amdgcn_mfma_f32_16x16x32_bf16(                 \
          A01, bfr[ni][1], acc[MI0][ni], 0, 0, 0);                            \
      acc[MI0 + 1][ni] = __builtin_amdgcn_mfma_f32_16x16x32_bf16(             \
          A10, bfr[ni][0], acc[MI0 + 1][ni], 0, 0, 0);                        \
      acc[MI0 + 1][ni] = __builtin_amdgcn_mfma_f32_16x16x32_bf16(             \
          A11, bfr[ni][1], acc[MI0 + 1][ni], 0, 0, 0);                        \
    }                                                                         \
    __builtin_amdgcn_s_setprio(0);

#define G256_SYNC_IN()                                                        \
    asm volatile("" ::: "memory");                                            \
    __builtin_amdgcn_s_barrier();                                             \
    asm volatile("s_waitcnt lgkmcnt(0)" ::: "memory");                        \
    __builtin_amdgcn_sched_barrier(0);

#define G256_SYNC_OUT()                                                       \
    asm volatile("" ::: "memory");                                            \
    __builtin_amdgcn_s_barrier();

    {   // phase 0: all B frags + A(0,1); stage B-half0 of t+1
      #pragma unroll
      for (int ni = 0; ni < 4; ++ni)
        #pragma unroll
        for (int s = 0; s < 2; ++s)
          bfr[ni][s] = ld(curB, wc * 64 + ni * 16 + l15, s);
      short8 a00 = ld(curA, wr * 128 + 0 * 16 + l15, 0);
      short8 a01 = ld(curA, wr * 128 + 0 * 16 + l15, 1);
      short8 a10 = ld(curA, wr * 128 + 1 * 16 + l15, 0);
      short8 a11 = ld(curA, wr * 128 + 1 * 16 + l15, 1);
      if (more) stage(nxt, t + 1, 2);
      G256_SYNC_IN();
      G256_MFMA16(0, a00, a01, a10, a11);
      G256_SYNC_OUT();
    }
    {   // phase 1: A(2,3); stage B-half1 of t+1
      short8 a00 = ld(curA, wr * 128 + 2 * 16 + l15, 0);
      short8 a01 = ld(curA, wr * 128 + 2 * 16 + l15, 1);
      short8 a10 = ld(curA, wr * 128 + 3 * 16 + l15, 0);
      short8 a11 = ld(curA, wr * 128 + 3 * 16 + l15, 1);
      if (more) stage(nxt, t + 1, 3);
      G256_SYNC_IN();
      G256_MFMA16(2, a00, a01, a10, a11);
      G256_SYNC_OUT();
    }
    {   // phase 2: A(4,5)
      short8 a00 = ld(curA, wr * 128 + 4 * 16 + l15, 0);
      short8 a01 = ld(curA, wr * 128 + 4 * 16 + l15, 1);
      short8 a10 = ld(curA, wr * 128 + 5 * 16 + l15, 0);
      short8 a11 = ld(curA, wr * 128 + 5 * 16 + l15, 1);
      G256_SYNC_IN();
      G256_MFMA16(4, a00, a01, a10, a11);
      G256_SYNC_OUT();
    }
    {   // phase 3: A(6,7)
      short8 a00 = ld(curA, wr * 128 + 6 * 16 + l15, 0);
      short8 a01 = ld(curA, wr * 128 + 6 * 16 + l15, 1);
      short8 a10 = ld(curA, wr * 128 + 7 * 16 + l15, 0);
      short8 a11 = ld(curA, wr * 128 + 7 * 16 + l15, 1);
      G256_SYNC_IN();
      G256_MFMA16(6, a00, a01, a10, a11);
      G256_SYNC_OUT();
    }
  }

  float* cfp = (EPI == 0 && bz) ? Cf2 : Cf;
  ushort_t* ub = Ub;
  if (EPI == 3) ub = Ub + (size_t)bz * M_ * D_;
  #pragma unroll
  for (int mi = 0; mi < 8; ++mi)
    #pragma unroll
    for (int ni = 0; ni < 4; ++ni)
      #pragma unroll
      for (int j = 0; j < 4; ++j) {
        int row = m0 + wr * 128 + mi * 16 + ((lane >> 4) << 2) + j;
        int col = n0 + wc * 64 + ni * 16 + l15;
        size_t idx = (size_t)row * N + col;
        float v = acc[mi][ni][j];
        if (EPI == 0) {
          cfp[idx] = v;
        } else if (EPI == 1) {
          float tt = v > 0.0f ? v : 0.0f;
          ub[idx] = f2bf(tt * tt);
        } else if (EPI == 3) {
          ub[idx] = f2bf(v);
        }
      }
}

// ============ 128x256 8-wave pipelined GEMM (D-output GEMMs), B [N][K] ==========
// N fixed 1024. EPI: 2 = Cf = X + acc
//                  4 = Cf = X2 + sigmoid(acc) * (X + Xb)
template <int EPI>
__global__ __launch_bounds__(512, 2)
void gemmB(const ushort_t* __restrict__ A, const ushort_t* __restrict__ Bt,
           int K, int ktn,
           float* __restrict__ Cf,
           const float* __restrict__ X, const float* __restrict__ X2,
           const float* __restrict__ Xb) {
  __shared__ alignas(16) ushort_t sA[2][128 * 64];
  __shared__ alignas(16) ushort_t sB[2][256 * 64];
  const int tid = threadIdx.x;
  const int lane = tid & 63;
  const int wave = tid >> 6;
  const int wr = wave >> 2, wc = wave & 3;      // 2 x 4 wave grid (64-row, 64-col)
  const int l15 = lane & 15;
  const int kb = (lane >> 4) << 4;
  int bx, by, zid;
  xcd_swz(gridDim.x, gridDim.y, bx, by, zid);
  const int m0 = bx * 128, n0 = by * 256;

  const ushort_t* gA = A + (size_t)m0 * K;
  const ushort_t* gB = Bt + (size_t)n0 * K;

  const int sr = tid >> 3;
  const int sc8 = (tid & 7) ^ (sr & 7);
  const int scb = (tid & 7) * 16;

  // h: 0,1 = A 64-row halves (1 round each); 2,3 = B 128-row halves (2 rounds)
  auto stage = [&](int dbuf, int kt, int h) {
    if (h < 2) {
      int row = h * 64 + sr;
      gl_lds16(gA + (size_t)row * K + (size_t)kt * 64 + sc8 * 8,
               (char*)sA[dbuf] + row * 128 + scb);
    } else {
      int rbase = (h - 2) * 128;
      #pragma unroll
      for (int i = 0; i < 2; ++i) {
        int row = rbase + i * 64 + sr;
        gl_lds16(gB + (size_t)row * K + (size_t)kt * 64 + sc8 * 8,
                 (char*)sB[dbuf] + row * 128 + scb);
      }
    }
  };

  auto ld = [&](const ushort_t* sbuf, int row, int s5) -> short8 {
    int cb = ((s5 << 6) + kb) ^ ((row & 7) << 4);
    return *(const short8*)((const char*)sbuf + row * 128 + cb);
  };

  f32x4 acc[4][4] = {};

  stage(0, 0, 0); stage(0, 0, 1); stage(0, 0, 2); stage(0, 0, 3);

  for (int t = 0; t < ktn; ++t) {
    const int cur = t & 1, nxt = cur ^ 1;
    const bool more = (t + 1 < ktn);
    if (more) {
      stage(nxt, t + 1, 0); stage(nxt, t + 1, 1);
      stage(nxt, t + 1, 2); stage(nxt, t + 1, 3);
    }
    if (more) asm volatile("s_waitcnt vmcnt(6)" ::: "memory");
    else      asm volatile("s_waitcnt vmcnt(0)" ::: "memory");
    __builtin_amdgcn_s_barrier();

    const ushort_t* curA = sA[cur];
    const ushort_t* curB = sB[cur];

    #pragma unroll
    for (int s = 0; s < 2; ++s) {   // 2 phases: one per k-half
      short8 av[4], bv[4];
      #pragma unroll
      for (int i = 0; i < 4; ++i) av[i] = ld(curA, wr * 64 + i * 16 + l15, s);
      #pragma unroll
      for (int i = 0; i < 4; ++i) bv[i] = ld(curB, wc * 64 + i * 16 + l15, s);
      asm volatile("" ::: "memory");
      __builtin_amdgcn_s_barrier();
      asm volatile("s_waitcnt lgkmcnt(0)" ::: "memory");
      __builtin_amdgcn_sched_barrier(0);
      __builtin_amdgcn_s_setprio(1);
      #pragma unroll
      for (int mi = 0; mi < 4; ++mi)
        #pragma unroll
        for (int ni = 0; ni < 4; ++ni)
          acc[mi][ni] = __builtin_amdgcn_mfma_f32_16x16x32_bf16(
              av[mi], bv[ni], acc[mi][ni], 0, 0, 0);
      __builtin_amdgcn_s_setprio(0);
      asm volatile("" ::: "memory");
      __builtin_amdgcn_s_barrier();
    }
  }

  #pragma unroll
  for (int mi = 0; mi < 4; ++mi)
    #pragma unroll
    for (int ni = 0; ni < 4; ++ni)
      #pragma unroll
      for (int j = 0; j < 4; ++j) {
        int row = m0 + wr * 64 + mi * 16 + ((lane >> 4) << 2) + j;
        int col = n0 + wc * 64 + ni * 16 + l15;
        size_t idx = (size_t)row * D_ + col;
        float v = acc[mi][ni][j];
        if (EPI == 2) {
          Cf[idx] = X[idx] + v;
        } else if (EPI == 4) {
          float s = 1.0f / (1.0f + __expf(-v));
          Cf[idx] = X2[idx] + s * (X[idx] + Xb[idx]);
        }
      }
}

// ---------------- launcher ----------------
extern "C" void kernel_launch(void* const* d_in, const int* in_sizes, int n_in,
                              void* d_out, int out_size, void* d_ws, size_t ws_size,
                              hipStream_t stream) {
  const float* x      = (const float*)d_in[0];
  const float* s_cm   = (const float*)d_in[1];
  const float* s_tm   = (const float*)d_in[2];
  const float* s_num  = (const float*)d_in[3];
  const float* s_den  = (const float*)d_in[4];
  const float* s_q    = (const float*)d_in[5];
  const float* ln1_g  = (const float*)d_in[6];
  const float* ln1_b  = (const float*)d_in[7];
  const float* ln2_g  = (const float*)d_in[8];
  const float* ln2_b  = (const float*)d_in[9];
  const float* tmk    = (const float*)d_in[10];
  const float* tmv    = (const float*)d_in[11];
  const float* tmr    = (const float*)d_in[12];
  const float* tm_kw  = (const float*)d_in[13];
  const float* tm_vw  = (const float*)d_in[14];
  const float* tm_rw  = (const float*)d_in[15];
  const float* tdec   = (const float*)d_in[16];
  const float* tfirst = (const float*)d_in[17];
  const float* out_w  = (const float*)d_in[18];
  const float* cmk    = (const float*)d_in[19];
  const float* cmr    = (const float*)d_in[20];
  const float* cm_kw  = (const float*)d_in[21];
  const float* cm_vw  = (const float*)d_in[22];
  const float* cm_rw  = (const float*)d_in[23];

  float* out   = (float*)d_out;
  float* o_x   = out;
  float* o_h2l = out + (size_t)M_ * D_;
  float* o_hl  = o_h2l + B_ * D_;
  float* o_num = o_hl + B_ * D_;
  float* o_den = o_num + B_ * D_;
  float* o_q   = o_den + B_ * D_;

  char* W = (char*)d_ws;
  const size_t MB = 1024 * 1024;
  ushort_t* w_tmk = (ushort_t*)(W + 0 * MB);   // [w_tmk | w_tmv contiguous]
  ushort_t* w_tmv = (ushort_t*)(W + 2 * MB);
  ushort_t* w_tmr = (ushort_t*)(W + 4 * MB);
  ushort_t* w_out = (ushort_t*)(W + 6 * MB);
  ushort_t* w_cmk = (ushort_t*)(W + 8 * MB);
  ushort_t* w_cmv = (ushort_t*)(W + 16 * MB);
  ushort_t* w_cmr = (ushort_t*)(W + 24 * MB);
  // scan scratch 26..29MB
  float* cn = (float*)(W + 26 * MB + 0 * 512 * 1024);
  float* cd = (float*)(W + 26 * MB + 1 * 512 * 1024);
  float* cq = (float*)(W + 26 * MB + 2 * 512 * 1024);
  float* pn = (float*)(W + 26 * MB + 3 * 512 * 1024);
  float* pd = (float*)(W + 26 * MB + 4 * 512 * 1024);
  float* pq = (float*)(W + 26 * MB + 5 * 512 * 1024);
  ushort_t* xk    = (ushort_t*)(W + 32 * MB);  // [xk | xv contiguous M*D bf16]
  ushort_t* xv    = (ushort_t*)(W + 48 * MB);
  ushort_t* xr    = (ushort_t*)(W + 64 * MB);
  ushort_t* kbuf  = (ushort_t*)(W + 80 * MB);  // [kbuf | vbuf contiguous M*D bf16]
  ushort_t* vbuf  = (ushort_t*)(W + 96 * MB);
  ushort_t* kk    = (ushort_t*)(W + 128 * MB); // bf16 M*F (64MB)
  float*    ra    = (float*)(W + 32 * MB);     // f32 32MB: xk+xv region (dead after k+v GEMM)
  float*    rb    = (float*)(W + 128 * MB);    // f32 32MB: kk region (dead until cm_kw)
  float*    kv_a  = (float*)(W + 64 * MB);     // f32 32MB (xr+kbuf, dead after out_w/scan)
  float*    kv_b  = (float*)(W + 96 * MB);     // f32 32MB (vbuf+, dead after scan)
  ushort_t* rwkv  = xr;               // reuse (xr dead after r GEMM)
  ushort_t* xk2   = xk;               // reuse (after part3)
  ushort_t* xr2   = xv;               // reuse

  dim3 tb(32, 8);
  // weight convert + transpose (bf16, [N][K]); 5 DxD batched + the two F weights
  tconv5<<<dim3(D_/32, D_/32, 5), tb, 0, stream>>>(tm_kw, tm_vw, tm_rw, out_w, cm_rw,
                                                   w_tmk, w_tmv, w_tmr, w_out, w_cmr);
  tconv<<<dim3(F_/32, D_/32), tb, 0, stream>>>(cm_kw, w_cmk, D_, F_);
  tconv<<<dim3(D_/32, F_/32), tb, 0, stream>>>(cm_vw, w_cmv, F_, D_);

  // time-mix path: fused LN1 + token-shift mix -> xk,xv,xr (bf16)
  ln_mix<3><<<M_, 256, 0, stream>>>(x, s_tm, ln1_g, ln1_b, tmk, tmv, tmr,
                                    xk, xv, xr, o_hl);
  // k+v batched (z=0 k, z=1 v): grid 256 = 1 exact round -> bf16 kbuf/vbuf
  gemm256<3><<<dim3(M_/256, D_/256, 2), 512, 0, stream>>>(
      xk, w_tmk, D_, D_, D_/64, nullptr, nullptr, kbuf);
  // r split-K=2: grid 256 = 1 exact round -> f32 partials ra, rb
  gemm256<0><<<dim3(M_/256, D_/256, 2), 512, 0, stream>>>(
      xr, w_tmr, D_, D_, D_/128, ra, rb, nullptr);

  // chunked parallel WKV scan (bf16 k/v; r = sigmoid(ra+rb) in part3)
  wkv_part1<<<(NC_ * B_ * D_) / 256, 256, 0, stream>>>(kbuf, vbuf, tdec, cn, cd, cq);
  wkv_part2<<<(B_ * D_) / 256, 256, 0, stream>>>(cn, cd, cq, s_num, s_den, s_q, tdec,
                                                 pn, pd, pq, o_num, o_den, o_q);
  wkv_part3<<<(NC_ * B_ * D_) / 256, 256, 0, stream>>>(kbuf, vbuf, ra, rb, pn, pd, pq,
                                                       tdec, tfirst, rwkv);

  // out_w + residual: o_x = x + (r*wkv)@out_w   (256 blocks = 1 exact round)
  gemmB<2><<<dim3(M_/128, D_/256, 1), 512, 0, stream>>>(
      rwkv, w_out, D_, D_/64, o_x, x, nullptr, nullptr);

  // channel-mix path: fused LN2 + mix -> xk2, xr2
  ln_mix<2><<<M_, 256, 0, stream>>>(o_x, s_cm, ln2_g, ln2_b, cmk, nullptr, cmr,
                                    xk2, nullptr, xr2, o_h2l);
  // cm_kw: [M,D]@[D,F] -> relu^2 -> bf16 kk   (512 blocks = 2 exact rounds)
  gemm256<1><<<dim3(M_/256, F_/256, 1), 512, 0, stream>>>(
      xk2, w_cmk, F_, D_, D_/64, nullptr, nullptr, kk);
  // cm_vw: [M,F]@[F,D] split-K=2 -> kv_a + kv_b (256 blocks = 1 exact round)
  gemm256<0><<<dim3(M_/256, D_/256, 2), 512, 0, stream>>>(
      kk, w_cmv, D_, F_, F_/128, kv_a, kv_b, nullptr);
  // cm_rw + gate + residual: o_x = o_x + sigmoid(acc)*(kv_a+kv_b)  (256 blocks)
  gemmB<4><<<dim3(M_/128, D_/256, 1), 512, 0, stream>>>(
      xr2, w_cmr, D_, D_/64, o_x, kv_a, o_x, kv_b);
}